// Round 2
// baseline (225.239 us; speedup 1.0000x reference)
//
#include <hip/hip_runtime.h>
#include <stdint.h>

// Problem constants
#define B_      4
#define C_      3
#define H_      1024
#define W_      1024
#define OH_     31          // (1024-64)/32 + 1
#define NT_     32          // 32x32 tiles per image dim
#define NP_     3844        // B * OH * OH
#define NPOSPB_ 961         // OH*OH
#define NPPAD_  4096
#define EPS_    1e-5f

// ws layout (float offsets)
#define OFF_TILE  0         // 4 planes * 12 bc * 32 * 32 = 49152
#define OFF_STATS 49152     // 128 (s1 sum[32], s1 sq[32], s2 sum[32], s2 sq[32])
#define OFF_MX    49280     // 3 * 3844
#define OFF_MY    60812     // 3 * 3844
#define OFF_Y1    72344     // 32 * 4096
#define OFF_Y2    203416    // 32 * 4096
#define OFF_A     334488    // 3 * 3844
#define OFF_BV    346020    // 3 * 3844  (total 357552 floats = 1.43 MB)

// ---------------- K1: 32x32 tile partial sums of g, s, g*s, g*g ----------------
// grid = (B*C)*32 blocks, 256 threads. Block = (bc, 32-row strip = one tile row).
__global__ __launch_bounds__(256) void k1_tilesums(
        const float* __restrict__ g,
        const float* __restrict__ s,
        float* __restrict__ ws) {
    int blk = blockIdx.x;
    int bc = blk >> 5;        // 0..11
    int ty = blk & 31;        // tile row
    int t  = threadIdx.x;     // covers columns [4t, 4t+4)
    const float4* gp = (const float4*)(g + ((size_t)bc * H_ + (size_t)ty * 32) * W_);
    const float4* sp = (const float4*)(s + ((size_t)bc * H_ + (size_t)ty * 32) * W_);
    float sg = 0.f, ss = 0.f, sgs = 0.f, sgg = 0.f;
#pragma unroll 4
    for (int r = 0; r < 32; r++) {
        float4 gv = gp[r * (W_ / 4) + t];
        float4 sv = sp[r * (W_ / 4) + t];
        sg  += (gv.x + gv.y) + (gv.z + gv.w);
        ss  += (sv.x + sv.y) + (sv.z + sv.w);
        sgs += gv.x * sv.x + gv.y * sv.y + gv.z * sv.z + gv.w * sv.w;
        sgg += gv.x * gv.x + gv.y * gv.y + gv.z * gv.z + gv.w * gv.w;
    }
    // reduce groups of 8 lanes (8 threads * 4 cols = 32 cols = one tileX)
#pragma unroll
    for (int off = 4; off; off >>= 1) {
        sg  += __shfl_down(sg,  off, 8);
        ss  += __shfl_down(ss,  off, 8);
        sgs += __shfl_down(sgs, off, 8);
        sgg += __shfl_down(sgg, off, 8);
    }
    if ((t & 7) == 0) {
        int tx = t >> 3;
        int base = (bc * NT_ + ty) * NT_ + tx;
        ws[OFF_TILE + 0 * 12288 + base] = sg;
        ws[OFF_TILE + 1 * 12288 + base] = ss;
        ws[OFF_TILE + 2 * 12288 + base] = sgs;
        ws[OFF_TILE + 3 * 12288 + base] = sgg;
    }
    if (blk == 0 && t < 128) ws[OFF_STATS + t] = 0.f;   // zero stats accumulators
}

// ---------------- K2: box sums -> h(cov,var) -> conv1 -> y1 + stats1 ----------------
__global__ __launch_bounds__(256) void k2_conv1(
        const float* __restrict__ w1f,
        float* __restrict__ ws) {
    __shared__ float w[192];
    int t = threadIdx.x;
    if (t < 192) w[t] = w1f[t];
    __syncthreads();
    int p = blockIdx.x * 256 + t;
    bool ok = p < NP_;
    int pp = ok ? p : 0;
    int b = pp / NPOSPB_;
    int r = pp % NPOSPB_;
    int oy = r / OH_, ox = r % OH_;
    float h[6];
#pragma unroll
    for (int c = 0; c < C_; c++) {
        int bc = b * 3 + c;
        const float* t0 = ws + OFF_TILE + 0 * 12288 + (bc * NT_ + oy) * NT_ + ox;
        const float* t1 = ws + OFF_TILE + 1 * 12288 + (bc * NT_ + oy) * NT_ + ox;
        const float* t2 = ws + OFF_TILE + 2 * 12288 + (bc * NT_ + oy) * NT_ + ox;
        const float* t3 = ws + OFF_TILE + 3 * 12288 + (bc * NT_ + oy) * NT_ + ox;
        float Sg  = t0[0] + t0[1] + t0[NT_] + t0[NT_ + 1];
        float Ss  = t1[0] + t1[1] + t1[NT_] + t1[NT_ + 1];
        float Sgs = t2[0] + t2[1] + t2[NT_] + t2[NT_ + 1];
        float Sgg = t3[0] + t3[1] + t3[NT_] + t3[NT_ + 1];
        const float inv = 1.f / 4096.f;
        float mx = Sg * inv, my = Ss * inv;
        float cov = Sgs * inv - mx * my;
        float var = Sgg * inv - mx * mx;
        h[c] = cov; h[3 + c] = var;
        if (ok) { ws[OFF_MX + c * NP_ + pp] = mx; ws[OFF_MY + c * NP_ + pp] = my; }
    }
#pragma unroll
    for (int o = 0; o < 32; o++) {
        float y = 0.f;
#pragma unroll
        for (int i = 0; i < 6; i++) y += w[o * 6 + i] * h[i];
        if (ok) ws[OFF_Y1 + o * NPPAD_ + pp] = y;
        float yv = ok ? y : 0.f;
        float sv = yv, sq = yv * yv;
#pragma unroll
        for (int off = 32; off; off >>= 1) {
            sv += __shfl_down(sv, off, 64);
            sq += __shfl_down(sq, off, 64);
        }
        if ((t & 63) == 0) {
            atomicAdd(&ws[OFF_STATS + o], sv);
            atomicAdd(&ws[OFF_STATS + 32 + o], sq);
        }
    }
}

// ---------------- K3: BN1+ReLU -> conv2 -> y2 + stats2 ----------------
__global__ __launch_bounds__(256) void k3_conv2(
        const float* __restrict__ w2f,
        const float* __restrict__ g1f,
        const float* __restrict__ b1f,
        float* __restrict__ ws) {
    __shared__ float w[1024];
    __shared__ float sc[32], sh[32];
    int t = threadIdx.x;
    for (int i = t; i < 1024; i += 256) w[i] = w2f[i];
    if (t < 32) {
        float m = ws[OFF_STATS + t] * (1.f / NP_);
        float v = ws[OFF_STATS + 32 + t] * (1.f / NP_) - m * m;
        float scale = g1f[t] * rsqrtf(v + EPS_);
        sc[t] = scale; sh[t] = b1f[t] - m * scale;
    }
    __syncthreads();
    int p = blockIdx.x * 256 + t;
    bool ok = p < NP_;
    float z[32];
#pragma unroll
    for (int i = 0; i < 32; i++) {
        float y = ws[OFF_Y1 + i * NPPAD_ + p];   // p < 4096 = NPPAD_, in-bounds (pad is benign)
        z[i] = fmaxf(y * sc[i] + sh[i], 0.f);
    }
#pragma unroll
    for (int o = 0; o < 32; o++) {
        float y = 0.f;
#pragma unroll
        for (int i = 0; i < 32; i++) y += w[o * 32 + i] * z[i];
        if (ok) ws[OFF_Y2 + o * NPPAD_ + p] = y;
        float yv = ok ? y : 0.f;
        float sv = yv, sq = yv * yv;
#pragma unroll
        for (int off = 32; off; off >>= 1) {
            sv += __shfl_down(sv, off, 64);
            sq += __shfl_down(sq, off, 64);
        }
        if ((t & 63) == 0) {
            atomicAdd(&ws[OFF_STATS + 64 + o], sv);
            atomicAdd(&ws[OFF_STATS + 96 + o], sq);
        }
    }
}

// ---------------- K4: BN2+ReLU -> conv3 -> A, b ----------------
__global__ __launch_bounds__(256) void k4_conv3(
        const float* __restrict__ w3f,
        const float* __restrict__ g2f,
        const float* __restrict__ b2f,
        float* __restrict__ ws) {
    __shared__ float w[96];
    __shared__ float sc[32], sh[32];
    int t = threadIdx.x;
    if (t < 96) w[t] = w3f[t];
    if (t >= 128 && t < 160) {
        int o = t - 128;
        float m = ws[OFF_STATS + 64 + o] * (1.f / NP_);
        float v = ws[OFF_STATS + 96 + o] * (1.f / NP_) - m * m;
        float scale = g2f[o] * rsqrtf(v + EPS_);
        sc[o] = scale; sh[o] = b2f[o] - m * scale;
    }
    __syncthreads();
    int p = blockIdx.x * 256 + t;
    if (p >= NP_) return;
    float z[32];
#pragma unroll
    for (int i = 0; i < 32; i++) {
        float y = ws[OFF_Y2 + i * NPPAD_ + p];
        z[i] = fmaxf(y * sc[i] + sh[i], 0.f);
    }
#pragma unroll
    for (int c = 0; c < 3; c++) {
        float a = 0.f;
#pragma unroll
        for (int i = 0; i < 32; i++) a += w[c * 32 + i] * z[i];
        float mx = ws[OFF_MX + c * NP_ + p];
        float my = ws[OFF_MY + c * NP_ + p];
        ws[OFF_A  + c * NP_ + p] = a;
        ws[OFF_BV + c * NP_ + p] = my - a * mx;
    }
}

// ---------------- K5: bilinear upsample (align_corners) + out = A*g + b ----------------
// grid = B*C*H blocks (one per output row), 256 threads (4 px each, 16B vec I/O)
__global__ __launch_bounds__(256) void k5_final(
        const float* __restrict__ g,
        const float* __restrict__ ws,
        float* __restrict__ out) {
    int blk = blockIdx.x;
    int y  = blk & 1023;
    int bc = blk >> 10;
    int b = bc / 3, c = bc % 3;
    float fy = (float)y * (30.f / 1023.f);
    int y0 = (int)fy;
    float wy = fy - (float)y0;
    int y1i = min(y0 + 1, 30);
    const float* A0 = ws + OFF_A  + c * NP_ + b * NPOSPB_ + y0  * OH_;
    const float* A1 = ws + OFF_A  + c * NP_ + b * NPOSPB_ + y1i * OH_;
    const float* B0 = ws + OFF_BV + c * NP_ + b * NPOSPB_ + y0  * OH_;
    const float* B1 = ws + OFF_BV + c * NP_ + b * NPOSPB_ + y1i * OH_;
    int t = threadIdx.x;
    size_t rowoff = ((size_t)bc * H_ + (size_t)y) * W_;
    const float4* gp = (const float4*)(g + rowoff);
    float4* op = (float4*)(out + rowoff);
    float4 gv = gp[t];
    float go[4] = { gv.x, gv.y, gv.z, gv.w };
    float r[4];
#pragma unroll
    for (int j = 0; j < 4; j++) {
        int x = t * 4 + j;
        float fx = (float)x * (30.f / 1023.f);
        int x0 = (int)fx;
        float wx = fx - (float)x0;
        int x1 = min(x0 + 1, 30);
        float a  = (A0[x0] * (1.f - wx) + A0[x1] * wx) * (1.f - wy)
                 + (A1[x0] * (1.f - wx) + A1[x1] * wx) * wy;
        float bb = (B0[x0] * (1.f - wx) + B0[x1] * wx) * (1.f - wy)
                 + (B1[x0] * (1.f - wx) + B1[x1] * wx) * wy;
        r[j] = a * go[j] + bb;
    }
    float4 ov; ov.x = r[0]; ov.y = r[1]; ov.z = r[2]; ov.w = r[3];
    op[t] = ov;
}

extern "C" void kernel_launch(void* const* d_in, const int* in_sizes, int n_in,
                              void* d_out, int out_size, void* d_ws, size_t ws_size,
                              hipStream_t stream) {
    const float* guide = (const float*)d_in[0];
    const float* src   = (const float*)d_in[1];
    // d_in[2] = box_w (all ones) -- unused; N == 4096 everywhere (VALID padding)
    const float* w1 = (const float*)d_in[3];
    const float* g1 = (const float*)d_in[4];
    const float* b1 = (const float*)d_in[5];
    const float* w2 = (const float*)d_in[6];
    const float* g2 = (const float*)d_in[7];
    const float* b2 = (const float*)d_in[8];
    const float* w3 = (const float*)d_in[9];
    float* ws = (float*)d_ws;
    float* out = (float*)d_out;

    hipLaunchKernelGGL(k1_tilesums, dim3(B_ * C_ * 32), dim3(256), 0, stream, guide, src, ws);
    hipLaunchKernelGGL(k2_conv1,   dim3(16),           dim3(256), 0, stream, w1, ws);
    hipLaunchKernelGGL(k3_conv2,   dim3(16),           dim3(256), 0, stream, w2, g1, b1, ws);
    hipLaunchKernelGGL(k4_conv3,   dim3(16),           dim3(256), 0, stream, w3, g2, b2, ws);
    hipLaunchKernelGGL(k5_final,   dim3(B_ * C_ * H_), dim3(256), 0, stream, guide, ws, out);
}

// Round 4
// 222.823 us; speedup vs baseline: 1.0108x; 1.0108x over previous
//
#include <hip/hip_runtime.h>
#include <stdint.h>

// Problem constants
#define B_      4
#define C_      3
#define H_      1024
#define W_      1024
#define OH_     31          // (1024-64)/32 + 1
#define NHS_    64          // 16-row half-strips per image
#define NP_     3844        // B * OH * OH
#define NPOSPB_ 961         // OH*OH
#define NPPAD_  4096
#define EPS_    1e-5f

// ws layout (float offsets)
#define TILE_PLANE 24576    // 12 bc * 64 hs * 32 tx
#define OFF_TILE  0         // 4 planes * 24576 = 98304
#define OFF_STATS 98304     // 128 (s1 sum[32], s1 sq[32], s2 sum[32], s2 sq[32])
#define OFF_MX    98432     // 3 * 3844
#define OFF_MY    109964    // 3 * 3844
#define OFF_Y1    121496    // 32 * 4096
#define OFF_Y2    252568    // 32 * 4096
#define OFF_A     383640    // 3 * 3844
#define OFF_BV    395172    // 3 * 3844   (total 406704 floats = 1.63 MB)

typedef float f4 __attribute__((ext_vector_type(4)));   // native vector: OK for nontemporal builtins

// ---------------- K1: 16-row half-strip partial sums of g, s, g*s, g*g per 32-col tile ----------------
// grid = (B*C)*64 = 768 blocks, 256 threads. Block = (bc, 16-row half-strip).
__global__ __launch_bounds__(256) void k1_tilesums(
        const float* __restrict__ g,
        const float* __restrict__ s,
        float* __restrict__ ws) {
    int blk = blockIdx.x;
    int bc = blk >> 6;        // 0..11
    int hs = blk & 63;        // half-strip (16 rows)
    int t  = threadIdx.x;     // covers columns [4t, 4t+4)
    const f4* gp = (const f4*)(g + ((size_t)bc * H_ + (size_t)hs * 16) * W_);
    const f4* sp = (const f4*)(s + ((size_t)bc * H_ + (size_t)hs * 16) * W_);
    float sg = 0.f, ss = 0.f, sgs = 0.f, sgg = 0.f;
#pragma unroll 4
    for (int r = 0; r < 16; r++) {
        f4 gv = gp[r * (W_ / 4) + t];
        f4 sv = __builtin_nontemporal_load(sp + r * (W_ / 4) + t);  // src read exactly once
        sg  += (gv.x + gv.y) + (gv.z + gv.w);
        ss  += (sv.x + sv.y) + (sv.z + sv.w);
        sgs += gv.x * sv.x + gv.y * sv.y + gv.z * sv.z + gv.w * sv.w;
        sgg += gv.x * gv.x + gv.y * gv.y + gv.z * gv.z + gv.w * gv.w;
    }
    // reduce groups of 8 lanes (8 threads * 4 cols = 32 cols = one tileX)
#pragma unroll
    for (int off = 4; off; off >>= 1) {
        sg  += __shfl_down(sg,  off, 8);
        ss  += __shfl_down(ss,  off, 8);
        sgs += __shfl_down(sgs, off, 8);
        sgg += __shfl_down(sgg, off, 8);
    }
    if ((t & 7) == 0) {
        int tx = t >> 3;
        int base = (bc * NHS_ + hs) * 32 + tx;
        ws[OFF_TILE + 0 * TILE_PLANE + base] = sg;
        ws[OFF_TILE + 1 * TILE_PLANE + base] = ss;
        ws[OFF_TILE + 2 * TILE_PLANE + base] = sgs;
        ws[OFF_TILE + 3 * TILE_PLANE + base] = sgg;
    }
    if (blk == 0 && t < 128) ws[OFF_STATS + t] = 0.f;   // zero stats accumulators
}

// ---------------- K2: box sums -> h(cov,var) -> conv1 -> y1 + stats1 ----------------
// Window (oy,ox) = half-strips oy*2..oy*2+3, tile-cols ox..ox+1 (8 partials).
__global__ __launch_bounds__(256) void k2_conv1(
        const float* __restrict__ w1f,
        float* __restrict__ ws) {
    __shared__ float w[192];
    int t = threadIdx.x;
    if (t < 192) w[t] = w1f[t];
    __syncthreads();
    int p = blockIdx.x * 256 + t;
    bool ok = p < NP_;
    int pp = ok ? p : 0;
    int b = pp / NPOSPB_;
    int r = pp % NPOSPB_;
    int oy = r / OH_, ox = r % OH_;
    float h[6];
#pragma unroll
    for (int c = 0; c < C_; c++) {
        int bc = b * 3 + c;
        int base = (bc * NHS_ + oy * 2) * 32 + ox;
        float S[4];
#pragma unroll
        for (int pl = 0; pl < 4; pl++) {
            const float* tp = ws + OFF_TILE + pl * TILE_PLANE + base;
            S[pl] = ((tp[0]  + tp[1])  + (tp[32] + tp[33]))
                  + ((tp[64] + tp[65]) + (tp[96] + tp[97]));
        }
        const float inv = 1.f / 4096.f;
        float mx = S[0] * inv, my = S[1] * inv;
        float cov = S[2] * inv - mx * my;
        float var = S[3] * inv - mx * mx;
        h[c] = cov; h[3 + c] = var;
        if (ok) { ws[OFF_MX + c * NP_ + pp] = mx; ws[OFF_MY + c * NP_ + pp] = my; }
    }
#pragma unroll
    for (int o = 0; o < 32; o++) {
        float y = 0.f;
#pragma unroll
        for (int i = 0; i < 6; i++) y += w[o * 6 + i] * h[i];
        if (ok) ws[OFF_Y1 + o * NPPAD_ + pp] = y;
        float yv = ok ? y : 0.f;
        float sv = yv, sq = yv * yv;
#pragma unroll
        for (int off = 32; off; off >>= 1) {
            sv += __shfl_down(sv, off, 64);
            sq += __shfl_down(sq, off, 64);
        }
        if ((t & 63) == 0) {
            atomicAdd(&ws[OFF_STATS + o], sv);
            atomicAdd(&ws[OFF_STATS + 32 + o], sq);
        }
    }
}

// ---------------- K3: BN1+ReLU -> conv2 -> y2 + stats2 ----------------
__global__ __launch_bounds__(256) void k3_conv2(
        const float* __restrict__ w2f,
        const float* __restrict__ g1f,
        const float* __restrict__ b1f,
        float* __restrict__ ws) {
    __shared__ float w[1024];
    __shared__ float sc[32], sh[32];
    int t = threadIdx.x;
    for (int i = t; i < 1024; i += 256) w[i] = w2f[i];
    if (t < 32) {
        float m = ws[OFF_STATS + t] * (1.f / NP_);
        float v = ws[OFF_STATS + 32 + t] * (1.f / NP_) - m * m;
        float scale = g1f[t] * rsqrtf(v + EPS_);
        sc[t] = scale; sh[t] = b1f[t] - m * scale;
    }
    __syncthreads();
    int p = blockIdx.x * 256 + t;
    bool ok = p < NP_;
    float z[32];
#pragma unroll
    for (int i = 0; i < 32; i++) {
        float y = ws[OFF_Y1 + i * NPPAD_ + p];   // p < 4096 = NPPAD_, in-bounds (pad is benign)
        z[i] = fmaxf(y * sc[i] + sh[i], 0.f);
    }
#pragma unroll
    for (int o = 0; o < 32; o++) {
        float y = 0.f;
#pragma unroll
        for (int i = 0; i < 32; i++) y += w[o * 32 + i] * z[i];
        if (ok) ws[OFF_Y2 + o * NPPAD_ + p] = y;
        float yv = ok ? y : 0.f;
        float sv = yv, sq = yv * yv;
#pragma unroll
        for (int off = 32; off; off >>= 1) {
            sv += __shfl_down(sv, off, 64);
            sq += __shfl_down(sq, off, 64);
        }
        if ((t & 63) == 0) {
            atomicAdd(&ws[OFF_STATS + 64 + o], sv);
            atomicAdd(&ws[OFF_STATS + 96 + o], sq);
        }
    }
}

// ---------------- K4: BN2+ReLU -> conv3 -> A, b ----------------
__global__ __launch_bounds__(256) void k4_conv3(
        const float* __restrict__ w3f,
        const float* __restrict__ g2f,
        const float* __restrict__ b2f,
        float* __restrict__ ws) {
    __shared__ float w[96];
    __shared__ float sc[32], sh[32];
    int t = threadIdx.x;
    if (t < 96) w[t] = w3f[t];
    if (t >= 128 && t < 160) {
        int o = t - 128;
        float m = ws[OFF_STATS + 64 + o] * (1.f / NP_);
        float v = ws[OFF_STATS + 96 + o] * (1.f / NP_) - m * m;
        float scale = g2f[o] * rsqrtf(v + EPS_);
        sc[o] = scale; sh[o] = b2f[o] - m * scale;
    }
    __syncthreads();
    int p = blockIdx.x * 256 + t;
    if (p >= NP_) return;
    float z[32];
#pragma unroll
    for (int i = 0; i < 32; i++) {
        float y = ws[OFF_Y2 + i * NPPAD_ + p];
        z[i] = fmaxf(y * sc[i] + sh[i], 0.f);
    }
#pragma unroll
    for (int c = 0; c < 3; c++) {
        float a = 0.f;
#pragma unroll
        for (int i = 0; i < 32; i++) a += w[c * 32 + i] * z[i];
        float mx = ws[OFF_MX + c * NP_ + p];
        float my = ws[OFF_MY + c * NP_ + p];
        ws[OFF_A  + c * NP_ + p] = a;
        ws[OFF_BV + c * NP_ + p] = my - a * mx;
    }
}

// ---------------- K5: bilinear upsample (align_corners) + out = A*g + b ----------------
// grid = B*C*H blocks (one per output row), 256 threads (4 px each, 16B vec I/O)
__global__ __launch_bounds__(256) void k5_final(
        const float* __restrict__ g,
        const float* __restrict__ ws,
        float* __restrict__ out) {
    int blk = blockIdx.x;
    int y  = blk & 1023;
    int bc = blk >> 10;
    int b = bc / 3, c = bc % 3;
    float fy = (float)y * (30.f / 1023.f);
    int y0 = (int)fy;
    float wy = fy - (float)y0;
    int y1i = min(y0 + 1, 30);
    const float* A0 = ws + OFF_A  + c * NP_ + b * NPOSPB_ + y0  * OH_;
    const float* A1 = ws + OFF_A  + c * NP_ + b * NPOSPB_ + y1i * OH_;
    const float* B0 = ws + OFF_BV + c * NP_ + b * NPOSPB_ + y0  * OH_;
    const float* B1 = ws + OFF_BV + c * NP_ + b * NPOSPB_ + y1i * OH_;
    int t = threadIdx.x;
    size_t rowoff = ((size_t)bc * H_ + (size_t)y) * W_;
    const f4* gp = (const f4*)(g + rowoff);
    f4* op = (f4*)(out + rowoff);
    f4 gv = gp[t];
    float go[4] = { gv.x, gv.y, gv.z, gv.w };
    float r[4];
#pragma unroll
    for (int j = 0; j < 4; j++) {
        int x = t * 4 + j;
        float fx = (float)x * (30.f / 1023.f);
        int x0 = (int)fx;
        float wx = fx - (float)x0;
        int x1 = min(x0 + 1, 30);
        float a  = (A0[x0] * (1.f - wx) + A0[x1] * wx) * (1.f - wy)
                 + (A1[x0] * (1.f - wx) + A1[x1] * wx) * wy;
        float bb = (B0[x0] * (1.f - wx) + B0[x1] * wx) * (1.f - wy)
                 + (B1[x0] * (1.f - wx) + B1[x1] * wx) * wy;
        r[j] = a * go[j] + bb;
    }
    f4 ov;
    ov.x = r[0]; ov.y = r[1]; ov.z = r[2]; ov.w = r[3];
    __builtin_nontemporal_store(ov, op + t);   // out never re-read
}

extern "C" void kernel_launch(void* const* d_in, const int* in_sizes, int n_in,
                              void* d_out, int out_size, void* d_ws, size_t ws_size,
                              hipStream_t stream) {
    const float* guide = (const float*)d_in[0];
    const float* src   = (const float*)d_in[1];
    // d_in[2] = box_w (all ones) -- unused; N == 4096 everywhere (VALID padding)
    const float* w1 = (const float*)d_in[3];
    const float* g1 = (const float*)d_in[4];
    const float* b1 = (const float*)d_in[5];
    const float* w2 = (const float*)d_in[6];
    const float* g2 = (const float*)d_in[7];
    const float* b2 = (const float*)d_in[8];
    const float* w3 = (const float*)d_in[9];
    float* ws = (float*)d_ws;
    float* out = (float*)d_out;

    hipLaunchKernelGGL(k1_tilesums, dim3(B_ * C_ * NHS_), dim3(256), 0, stream, guide, src, ws);
    hipLaunchKernelGGL(k2_conv1,   dim3(16),              dim3(256), 0, stream, w1, ws);
    hipLaunchKernelGGL(k3_conv2,   dim3(16),              dim3(256), 0, stream, w2, g1, b1, ws);
    hipLaunchKernelGGL(k4_conv3,   dim3(16),              dim3(256), 0, stream, w3, g2, b2, ws);
    hipLaunchKernelGGL(k5_final,   dim3(B_ * C_ * H_),    dim3(256), 0, stream, guide, ws, out);
}